// Round 5
// baseline (190.545 us; speedup 1.0000x reference)
//
#include <hip/hip_runtime.h>
#include <math.h>

// Problem constants (N=2, C=256, H=W=64, G=8, P=9, CG=32)
#define CC    256
#define HH    64
#define WW    64
#define HWSZ  4096
#define NPIX  8192
#define MT    16        // pixels per tile (one row segment, same h)
#define ASTR  264       // A-tile LDS row stride in bf16 elems (528 B)

typedef __attribute__((ext_vector_type(8))) short short8;
typedef __attribute__((ext_vector_type(4))) float f32x4;

__device__ __forceinline__ float silu_f(float x) { return x / (1.f + __expf(-x)); }

// fp32 -> bf16 round-to-nearest-even
__device__ __forceinline__ short f2bf(float f) {
    unsigned u = __float_as_uint(f);
    unsigned r = (u + 0x7fffu + ((u >> 16) & 1u)) >> 16;
    return (short)r;
}
__device__ __forceinline__ unsigned pk2(float a, float b) {
    return (unsigned)(unsigned short)f2bf(a) | ((unsigned)(unsigned short)f2bf(b) << 16);
}

// ---------------------------------------------------------------------------
// prep: bf16 weights (O,C) o-major; fused epilogue params
__global__ void k_prep(const float* __restrict__ cw, const float* __restrict__ ipw,
                       const float* __restrict__ offw, const float* __restrict__ maskw,
                       const float* __restrict__ opw,
                       const float* __restrict__ offb, const float* __restrict__ maskb,
                       const float* __restrict__ g1, const float* __restrict__ b1,
                       const float* __restrict__ m1, const float* __restrict__ v1,
                       const float* __restrict__ g2, const float* __restrict__ b2,
                       const float* __restrict__ m2, const float* __restrict__ v2,
                       short* __restrict__ Wc1b, short* __restrict__ Wipb,
                       short* __restrict__ Whb, short* __restrict__ Wopb,
                       float* __restrict__ bh, float* __restrict__ sc1, float* __restrict__ sh1,
                       float* __restrict__ sc2, float* __restrict__ sh2) {
    int o = blockIdx.x, c = threadIdx.x;
    Wc1b[o * CC + c] = f2bf(cw[o * CC + c]);
    Wipb[o * CC + c] = f2bf(ipw[c * CC + o]);
    float hv = 0.f;
    if (o < 144) hv = offw[c * 144 + o];
    else if (o < 216) hv = maskw[c * 72 + (o - 144)];
    Whb[o * CC + c] = f2bf(hv);
    Wopb[o * CC + c] = f2bf(opw[c * CC + o]);
    if (o == 0) {
        float bv = 0.f;
        if (c < 144) bv = offb[c];
        else if (c < 216) bv = maskb[c - 144];
        bh[c] = bv;
        float s1 = g1[c] * rsqrtf(v1[c] + 1e-3f);
        sc1[c] = s1; sh1[c] = b1[c] - m1[c] * s1;
        float s2 = g2[c] * rsqrtf(v2[c] + 1e-5f);
        sc2[c] = s2; sh2[c] = b2[c] - m2[c] * s2;
    }
}

// ---------------------------------------------------------------------------
// MFMA GEMM: 16 pixels x 256 outputs, K=256. Wave wv covers outputs [n0, n0+64).
// A from LDS (A[m=lane&15][k=quad*8+j]); B direct from global bf16 (O,C) o-major.
__device__ __forceinline__ void mfma_gemm(const short* As, const short* __restrict__ Wb,
                                          int lane, int n0, f32x4 acc[4]) {
    const int m = lane & 15, q = lane >> 4;
#pragma unroll
    for (int kk = 0; kk < 8; ++kk) {
        int c0 = kk * 32 + q * 8;
        short8 a = *(const short8*)(As + m * ASTR + c0);
#pragma unroll
        for (int nt = 0; nt < 4; ++nt) {
            short8 b = *(const short8*)(Wb + (size_t)(n0 + nt * 16 + m) * CC + c0);
            acc[nt] = __builtin_amdgcn_mfma_f32_16x16x32_bf16(a, b, acc[nt], 0, 0, 0);
        }
    }
}

// ---------------------------------------------------------------------------
// conv1(1x1, NCHW) + BN1 + SiLU -> y (NHWC fp32) ; fused inproj -> xp (fp32)
__global__ void k_conv_in(const float* __restrict__ x, const short* __restrict__ Wc1b,
                          const short* __restrict__ Wipb, const float* __restrict__ sc1,
                          const float* __restrict__ sh1, const float* __restrict__ ipb,
                          float* __restrict__ y, float* __restrict__ xp) {
    __shared__ __align__(16) short As[MT * ASTR];
    int tid = threadIdx.x;
    int pix0 = blockIdx.x * MT;
    int n = pix0 >> 12, hw0 = pix0 & (HWSZ - 1);
    const float* xn = x + (size_t)n * CC * HWSZ;
    {
        int i4 = (tid & 3) * 4;
#pragma unroll
        for (int rep = 0; rep < 4; ++rep) {
            int c = (tid >> 2) + rep * 64;
            float4 v = *(const float4*)(xn + (size_t)c * HWSZ + hw0 + i4);
            As[(i4 + 0) * ASTR + c] = f2bf(v.x);
            As[(i4 + 1) * ASTR + c] = f2bf(v.y);
            As[(i4 + 2) * ASTR + c] = f2bf(v.z);
            As[(i4 + 3) * ASTR + c] = f2bf(v.w);
        }
    }
    __syncthreads();
    int lane = tid & 63, n0 = (tid >> 6) * 64;
    int col = lane & 15, qr = (lane >> 4) * 4;
    f32x4 acc[4];
#pragma unroll
    for (int nt = 0; nt < 4; ++nt) acc[nt] = (f32x4){0.f, 0.f, 0.f, 0.f};
    mfma_gemm(As, Wc1b, lane, n0, acc);
    __syncthreads();
#pragma unroll
    for (int nt = 0; nt < 4; ++nt) {
        int o = n0 + nt * 16 + col;
        float sc = sc1[o], sh = sh1[o];
#pragma unroll
        for (int r = 0; r < 4; ++r) {
            int pix = qr + r;
            float val = silu_f(acc[nt][r] * sc + sh);
            y[(size_t)(pix0 + pix) * CC + o] = val;
            As[pix * ASTR + o] = f2bf(val);
        }
    }
    __syncthreads();
#pragma unroll
    for (int nt = 0; nt < 4; ++nt) acc[nt] = (f32x4){0.f, 0.f, 0.f, 0.f};
    mfma_gemm(As, Wipb, lane, n0, acc);
#pragma unroll
    for (int nt = 0; nt < 4; ++nt) {
        int o = n0 + nt * 16 + col;
        float bo = ipb[o];
#pragma unroll
        for (int r = 0; r < 4; ++r)
            xp[(size_t)(pix0 + qr + r) * CC + o] = acc[nt][r] + bo;
    }
}

// ---------------------------------------------------------------------------
// fused tail: dw3x3+LN+GELU -> heads GEMM -> softmax -> DCN gather -> outproj
// One 16-pixel row-tile per block; everything tile-local stays in LDS.
__global__ void k_tail(const float* __restrict__ y, const float* __restrict__ xp,
                       const float* __restrict__ dww, const float* __restrict__ dwb,
                       const float* __restrict__ lng, const float* __restrict__ lnb,
                       const short* __restrict__ Whb, const float* __restrict__ bh,
                       const short* __restrict__ Wopb, const float* __restrict__ opb,
                       const float* __restrict__ sc2, const float* __restrict__ sh2,
                       float* __restrict__ out) {
    __shared__ __align__(16) short As[MT * ASTR];
    __shared__ __align__(16) float buf[4672];
    float* ml   = buf;          // 16*76  mask logits
    float* loff = buf + 1216;   // 16*144 offsets
    float* lm   = buf + 3520;   // 16*72  softmaxed mask
    float* xs   = buf;          // 16*260 overlay (phase 5 only)

    int tid = threadIdx.x;
    int lane = tid & 63, wv = tid >> 6;
    int pix0 = blockIdx.x * MT;
    int n = pix0 >> 12, hw0 = pix0 & (HWSZ - 1);
    int h = hw0 >> 6, w0 = hw0 & 63;     // w0 in {0,16,32,48}; all 16 pixels share row h
    int c0 = lane * 4;

    // ---- phase 1: depthwise 3x3 + bias + LN + GELU for pixels wv*4..wv*4+3 -> As (bf16)
    {
        float wloc[36];
        const float4* wp4 = (const float4*)(dww + c0 * 9);
#pragma unroll
        for (int k = 0; k < 9; ++k) ((float4*)wloc)[k] = wp4[k];
        float4 dwbv = *(const float4*)(dwb + c0);
        float4 lngv = *(const float4*)(lng + c0);
        float4 lnbv = *(const float4*)(lnb + c0);
        const float* yn = y + (size_t)n * HWSZ * CC;
#pragma unroll
        for (int i = 0; i < 4; ++i) {
            int pix = wv * 4 + i;
            int w = w0 + pix;
            float4 acc = dwbv;
#pragma unroll
            for (int ky = 0; ky < 3; ++ky) {
                int yy = h + ky - 1;
                if (yy < 0 || yy >= HH) continue;
#pragma unroll
                for (int kx = 0; kx < 3; ++kx) {
                    int xx = w + kx - 1;
                    if (xx < 0 || xx >= WW) continue;
                    float4 yv = *(const float4*)(yn + (size_t)((yy << 6) + xx) * CC + c0);
                    int t = ky * 3 + kx;
                    acc.x += yv.x * wloc[0 * 9 + t];
                    acc.y += yv.y * wloc[1 * 9 + t];
                    acc.z += yv.z * wloc[2 * 9 + t];
                    acc.w += yv.w * wloc[3 * 9 + t];
                }
            }
            float s1 = acc.x + acc.y + acc.z + acc.w;
            float s2 = acc.x * acc.x + acc.y * acc.y + acc.z * acc.z + acc.w * acc.w;
#pragma unroll
            for (int off = 32; off > 0; off >>= 1) {
                s1 += __shfl_xor(s1, off);
                s2 += __shfl_xor(s2, off);
            }
            float mu = s1 * (1.f / 256.f);
            float var = s2 * (1.f / 256.f) - mu * mu;
            float rs = rsqrtf(var + 1e-5f);
            float4 zv;
            zv.x = (acc.x - mu) * rs * lngv.x + lnbv.x;
            zv.y = (acc.y - mu) * rs * lngv.y + lnbv.y;
            zv.z = (acc.z - mu) * rs * lngv.z + lnbv.z;
            zv.w = (acc.w - mu) * rs * lngv.w + lnbv.w;
            zv.x = 0.5f * zv.x * (1.f + erff(zv.x * 0.70710678118654752f));
            zv.y = 0.5f * zv.y * (1.f + erff(zv.y * 0.70710678118654752f));
            zv.z = 0.5f * zv.z * (1.f + erff(zv.z * 0.70710678118654752f));
            zv.w = 0.5f * zv.w * (1.f + erff(zv.w * 0.70710678118654752f));
            *(uint2*)(As + pix * ASTR + c0) = make_uint2(pk2(zv.x, zv.y), pk2(zv.z, zv.w));
        }
    }
    __syncthreads();

    // ---- phase 2: heads GEMM -> loff / ml (LDS only)
    int n0 = wv * 64;
    int col = lane & 15, qr = (lane >> 4) * 4;
    {
        f32x4 acc[4];
#pragma unroll
        for (int nt = 0; nt < 4; ++nt) acc[nt] = (f32x4){0.f, 0.f, 0.f, 0.f};
        mfma_gemm(As, Whb, lane, n0, acc);
#pragma unroll
        for (int nt = 0; nt < 4; ++nt) {
            int o = n0 + nt * 16 + col;
            float bo = bh[o];
#pragma unroll
            for (int r = 0; r < 4; ++r) {
                float v = acc[nt][r] + bo;
                int pix = qr + r;
                if (o < 144) loff[pix * 144 + o] = v;
                else if (o < 216) ml[pix * 76 + (o - 144)] = v;
            }
        }
    }
    __syncthreads();

    // ---- phase 3: per-group softmax -> lm
    if (tid < 128) {
        int pi = tid >> 3, g = tid & 7;
        const float* row = ml + pi * 76 + g * 9;
        float mx = -1e30f;
#pragma unroll
        for (int p = 0; p < 9; ++p) mx = fmaxf(mx, row[p]);
        float e[9], s = 0.f;
#pragma unroll
        for (int p = 0; p < 9; ++p) { e[p] = __expf(row[p] - mx); s += e[p]; }
        float inv = 1.f / s;
        float* mp = lm + pi * 72 + g * 9;
#pragma unroll
        for (int p = 0; p < 9; ++p) mp[p] = e[p] * inv;
    }
    __syncthreads();

    // ---- phase 4: DCN bilinear gather -> As (bf16). Wave handles 4 pixels, lane = 4 channels.
    {
        int g = lane >> 3;
        const float* xpn = xp + (size_t)n * HWSZ * CC;
#pragma unroll
        for (int i = 0; i < 4; ++i) {
            int pix = wv * 4 + i;
            int w = w0 + pix;
            float4 acc = make_float4(0.f, 0.f, 0.f, 0.f);
#pragma unroll
            for (int p = 0; p < 9; ++p) {
                float ox = loff[pix * 144 + (g * 9 + p) * 2];
                float oy = loff[pix * 144 + (g * 9 + p) * 2 + 1];
                float px = (float)(w + p / 3) + ox;
                float py = (float)(h + p % 3) + oy;
                float fx = floorf(px), fy = floorf(py);
                float wx1 = px - fx, wy1 = py - fy;
                int x0 = (int)fx, y0 = (int)fy;
                int x1 = x0 + 1, y1 = y0 + 1;
                float mval = lm[pix * 72 + g * 9 + p];
                float w00 = (1.f - wx1) * (1.f - wy1) * mval;
                float w10 = wx1 * (1.f - wy1) * mval;
                float w01 = (1.f - wx1) * wy1 * mval;
                float w11 = wx1 * wy1 * mval;
                if (x0 >= 1 && x0 <= WW && y0 >= 1 && y0 <= HH) {
                    float4 s = *(const float4*)(xpn + (size_t)(((y0 - 1) << 6) + (x0 - 1)) * CC + c0);
                    acc.x += w00 * s.x; acc.y += w00 * s.y; acc.z += w00 * s.z; acc.w += w00 * s.w;
                }
                if (x1 >= 1 && x1 <= WW && y0 >= 1 && y0 <= HH) {
                    float4 s = *(const float4*)(xpn + (size_t)(((y0 - 1) << 6) + (x1 - 1)) * CC + c0);
                    acc.x += w10 * s.x; acc.y += w10 * s.y; acc.z += w10 * s.z; acc.w += w10 * s.w;
                }
                if (x0 >= 1 && x0 <= WW && y1 >= 1 && y1 <= HH) {
                    float4 s = *(const float4*)(xpn + (size_t)(((y1 - 1) << 6) + (x0 - 1)) * CC + c0);
                    acc.x += w01 * s.x; acc.y += w01 * s.y; acc.z += w01 * s.z; acc.w += w01 * s.w;
                }
                if (x1 >= 1 && x1 <= WW && y1 >= 1 && y1 <= HH) {
                    float4 s = *(const float4*)(xpn + (size_t)(((y1 - 1) << 6) + (x1 - 1)) * CC + c0);
                    acc.x += w11 * s.x; acc.y += w11 * s.y; acc.z += w11 * s.z; acc.w += w11 * s.w;
                }
            }
            *(uint2*)(As + pix * ASTR + c0) = make_uint2(pk2(acc.x, acc.y), pk2(acc.z, acc.w));
        }
    }
    __syncthreads();

    // ---- phase 5: outproj GEMM + BN2 + SiLU -> NCHW store via LDS transpose
    {
        f32x4 acc[4];
#pragma unroll
        for (int nt = 0; nt < 4; ++nt) acc[nt] = (f32x4){0.f, 0.f, 0.f, 0.f};
        mfma_gemm(As, Wopb, lane, n0, acc);
#pragma unroll
        for (int nt = 0; nt < 4; ++nt) {
            int o = n0 + nt * 16 + col;
            float bo = opb[o], sc = sc2[o], sh = sh2[o];
#pragma unroll
            for (int r = 0; r < 4; ++r)
                xs[(qr + r) * 260 + o] = silu_f((acc[nt][r] + bo) * sc + sh);
        }
    }
    __syncthreads();
    float* on = out + (size_t)n * CC * HWSZ + (size_t)tid * HWSZ + hw0;
#pragma unroll
    for (int i4 = 0; i4 < MT; i4 += 4) {
        float4 ov;
        ov.x = xs[(i4 + 0) * 260 + tid];
        ov.y = xs[(i4 + 1) * 260 + tid];
        ov.z = xs[(i4 + 2) * 260 + tid];
        ov.w = xs[(i4 + 3) * 260 + tid];
        *(float4*)(on + i4) = ov;
    }
}

// ---------------------------------------------------------------------------
extern "C" void kernel_launch(void* const* d_in, const int* in_sizes, int n_in,
                              void* d_out, int out_size, void* d_ws, size_t ws_size,
                              hipStream_t stream) {
    const float* x        = (const float*)d_in[0];
    const float* conv1_w  = (const float*)d_in[1];
    const float* bn1_g    = (const float*)d_in[2];
    const float* bn1_b    = (const float*)d_in[3];
    const float* bn1_m    = (const float*)d_in[4];
    const float* bn1_v    = (const float*)d_in[5];
    const float* inproj_w = (const float*)d_in[6];
    const float* inproj_b = (const float*)d_in[7];
    const float* dw_w     = (const float*)d_in[8];
    const float* dw_b     = (const float*)d_in[9];
    const float* ln_g     = (const float*)d_in[10];
    const float* ln_b     = (const float*)d_in[11];
    const float* off_w    = (const float*)d_in[12];
    const float* off_b    = (const float*)d_in[13];
    const float* mask_w   = (const float*)d_in[14];
    const float* mask_b   = (const float*)d_in[15];
    const float* outproj_w = (const float*)d_in[16];
    const float* outproj_b = (const float*)d_in[17];
    const float* bn2_g    = (const float*)d_in[18];
    const float* bn2_b    = (const float*)d_in[19];
    const float* bn2_m    = (const float*)d_in[20];
    const float* bn2_v    = (const float*)d_in[21];
    float* out = (float*)d_out;

    short* Wc1b = (short*)d_ws;            // 65536 shorts each
    short* Wipb = Wc1b + 65536;
    short* Whb  = Wipb + 65536;
    short* Wopb = Whb + 65536;
    float* fp   = (float*)(Wopb + 65536);
    float* bh   = fp;
    float* sc1  = bh + 256;
    float* sh1  = sc1 + 256;
    float* sc2  = sh1 + 256;
    float* sh2  = sc2 + 256;
    float* y    = sh2 + 256;               // 2097152 (NHWC fp32)
    float* xp   = y + 2097152;             // 2097152 (NHWC fp32)

    k_prep<<<dim3(CC), dim3(CC), 0, stream>>>(conv1_w, inproj_w, off_w, mask_w, outproj_w,
                                              off_b, mask_b, bn1_g, bn1_b, bn1_m, bn1_v,
                                              bn2_g, bn2_b, bn2_m, bn2_v,
                                              Wc1b, Wipb, Whb, Wopb, bh, sc1, sh1, sc2, sh2);
    k_conv_in<<<dim3(NPIX / MT), dim3(256), 0, stream>>>(x, Wc1b, Wipb, sc1, sh1, inproj_b, y, xp);
    k_tail<<<dim3(NPIX / MT), dim3(256), 0, stream>>>(y, xp, dw_w, dw_b, ln_g, ln_b,
                                                      Whb, bh, Wopb, outproj_b, sc2, sh2, out);
}

// Round 6
// 166.933 us; speedup vs baseline: 1.1414x; 1.1414x over previous
//
#include <hip/hip_runtime.h>
#include <math.h>

// Problem constants (N=2, C=256, H=W=64, G=8, P=9, CG=32)
#define CC    256
#define HH    64
#define WW    64
#define HWSZ  4096
#define NPIX  8192
#define MT    16        // pixels per tile
#define ASTR  264       // A-tile LDS row stride in bf16 elems (528 B, 16B-multiple)

typedef __attribute__((ext_vector_type(8))) short short8;
typedef __attribute__((ext_vector_type(4))) float f32x4;

__device__ __forceinline__ float silu_f(float x) { return x / (1.f + __expf(-x)); }

// fp32 -> bf16 round-to-nearest-even
__device__ __forceinline__ short f2bf(float f) {
    unsigned u = __float_as_uint(f);
    unsigned r = (u + 0x7fffu + ((u >> 16) & 1u)) >> 16;
    return (short)r;
}
__device__ __forceinline__ unsigned pk2(float a, float b) {
    return (unsigned)(unsigned short)f2bf(a) | ((unsigned)(unsigned short)f2bf(b) << 16);
}

// ---------------------------------------------------------------------------
// prep: bf16 weights (O,C) o-major; fused epilogue params
__global__ void k_prep(const float* __restrict__ cw, const float* __restrict__ ipw,
                       const float* __restrict__ offw, const float* __restrict__ maskw,
                       const float* __restrict__ opw,
                       const float* __restrict__ offb, const float* __restrict__ maskb,
                       const float* __restrict__ g1, const float* __restrict__ b1,
                       const float* __restrict__ m1, const float* __restrict__ v1,
                       const float* __restrict__ g2, const float* __restrict__ b2,
                       const float* __restrict__ m2, const float* __restrict__ v2,
                       short* __restrict__ Wc1b, short* __restrict__ Wipb,
                       short* __restrict__ Whb, short* __restrict__ Wopb,
                       float* __restrict__ bh, float* __restrict__ sc1, float* __restrict__ sh1,
                       float* __restrict__ sc2, float* __restrict__ sh2) {
    int o = blockIdx.x, c = threadIdx.x;
    Wc1b[o * CC + c] = f2bf(cw[o * CC + c]);
    Wipb[o * CC + c] = f2bf(ipw[c * CC + o]);
    float hv = 0.f;
    if (o < 144) hv = offw[c * 144 + o];
    else if (o < 216) hv = maskw[c * 72 + (o - 144)];
    Whb[o * CC + c] = f2bf(hv);
    Wopb[o * CC + c] = f2bf(opw[c * CC + o]);
    if (o == 0) {
        float bv = 0.f;
        if (c < 144) bv = offb[c];
        else if (c < 216) bv = maskb[c - 144];
        bh[c] = bv;
        float s1 = g1[c] * rsqrtf(v1[c] + 1e-3f);
        sc1[c] = s1; sh1[c] = b1[c] - m1[c] * s1;
        float s2 = g2[c] * rsqrtf(v2[c] + 1e-5f);
        sc2[c] = s2; sh2[c] = b2[c] - m2[c] * s2;
    }
}

// ---------------------------------------------------------------------------
// 8-wave MFMA helpers: wave wv covers outputs [wv*32, wv*32+32) as 2 n-tiles of 16.
// B prefetched to registers (issued BEFORE the barrier so L2 latency drains under it).
__device__ __forceinline__ void prefetch_b(const short* __restrict__ Wb, int lane, int n0,
                                           short8 bf[8][2]) {
    const int m = lane & 15, q = lane >> 4;
#pragma unroll
    for (int kk = 0; kk < 8; ++kk) {
        int c0 = kk * 32 + q * 8;
#pragma unroll
        for (int nt = 0; nt < 2; ++nt)
            bf[kk][nt] = *(const short8*)(Wb + (size_t)(n0 + nt * 16 + m) * CC + c0);
    }
}
__device__ __forceinline__ void mfma_acc(const short* As, const short8 bf[8][2],
                                         int lane, f32x4 acc[2]) {
    const int m = lane & 15, q = lane >> 4;
#pragma unroll
    for (int kk = 0; kk < 8; ++kk) {
        short8 a = *(const short8*)(As + m * ASTR + kk * 32 + q * 8);
#pragma unroll
        for (int nt = 0; nt < 2; ++nt)
            acc[nt] = __builtin_amdgcn_mfma_f32_16x16x32_bf16(a, bf[kk][nt], acc[nt], 0, 0, 0);
    }
}

// ---------------------------------------------------------------------------
// conv1(1x1, NCHW) + BN1 + SiLU -> y (NHWC fp32) ; fused inproj -> xp (fp32)
__global__ __launch_bounds__(512, 4) void k_conv_in(
        const float* __restrict__ x, const short* __restrict__ Wc1b,
        const short* __restrict__ Wipb, const float* __restrict__ sc1,
        const float* __restrict__ sh1, const float* __restrict__ ipb,
        float* __restrict__ y, float* __restrict__ xp) {
    __shared__ __align__(16) short As[MT * ASTR];
    int tid = threadIdx.x, lane = tid & 63, wv = tid >> 6;
    int pix0 = blockIdx.x * MT;
    int n = pix0 >> 12, hw0 = pix0 & (HWSZ - 1);
    int n0 = wv * 32;
    short8 bf[8][2];
    prefetch_b(Wc1b, lane, n0, bf);          // in flight during staging + barrier
    const float* xn = x + (size_t)n * CC * HWSZ;
#pragma unroll
    for (int rep = 0; rep < 2; ++rep) {
        int f = tid + rep * 512;             // 0..1023 float4s of the 16x256 tile
        int c = f >> 2, i4 = (f & 3) * 4;
        float4 v = *(const float4*)(xn + (size_t)c * HWSZ + hw0 + i4);
        As[(i4 + 0) * ASTR + c] = f2bf(v.x);
        As[(i4 + 1) * ASTR + c] = f2bf(v.y);
        As[(i4 + 2) * ASTR + c] = f2bf(v.z);
        As[(i4 + 3) * ASTR + c] = f2bf(v.w);
    }
    __syncthreads();
    f32x4 acc[2];
    acc[0] = (f32x4){0.f, 0.f, 0.f, 0.f};
    acc[1] = (f32x4){0.f, 0.f, 0.f, 0.f};
    mfma_acc(As, bf, lane, acc);
    __syncthreads();                          // As consumed by GEMM1
    prefetch_b(Wipb, lane, n0, bf);           // GEMM2 B in flight during epilogue+barrier
    int col = lane & 15, qr = (lane >> 4) * 4;
#pragma unroll
    for (int nt = 0; nt < 2; ++nt) {
        int o = n0 + nt * 16 + col;
        float sc = sc1[o], sh = sh1[o];
#pragma unroll
        for (int r = 0; r < 4; ++r) {
            int pix = qr + r;
            float val = silu_f(acc[nt][r] * sc + sh);
            y[(size_t)(pix0 + pix) * CC + o] = val;
            As[pix * ASTR + o] = f2bf(val);
        }
    }
    __syncthreads();
    acc[0] = (f32x4){0.f, 0.f, 0.f, 0.f};
    acc[1] = (f32x4){0.f, 0.f, 0.f, 0.f};
    mfma_acc(As, bf, lane, acc);
#pragma unroll
    for (int nt = 0; nt < 2; ++nt) {
        int o = n0 + nt * 16 + col;
        float bo = ipb[o];
#pragma unroll
        for (int r = 0; r < 4; ++r)
            xp[(size_t)(pix0 + qr + r) * CC + o] = acc[nt][r] + bo;
    }
}

// ---------------------------------------------------------------------------
// fused tail: dw3x3+LN+GELU -> heads GEMM -> softmax -> DCN gather -> outproj
// 512 threads (8 waves), 16-pixel row tile per block.
__global__ __launch_bounds__(512, 4) void k_tail(
        const float* __restrict__ y, const float* __restrict__ xp,
        const float* __restrict__ dww, const float* __restrict__ dwb,
        const float* __restrict__ lng, const float* __restrict__ lnb,
        const short* __restrict__ Whb, const float* __restrict__ bh,
        const short* __restrict__ Wopb, const float* __restrict__ opb,
        const float* __restrict__ sc2, const float* __restrict__ sh2,
        float* __restrict__ out) {
    __shared__ __align__(16) short As[MT * ASTR];
    __shared__ __align__(16) float buf[4672];
    float* ml   = buf;          // 16*76  mask logits
    float* loff = buf + 1216;   // 16*144 offsets
    float* lm   = buf + 3520;   // 16*72  softmaxed mask
    float* xs   = buf;          // 16*260 overlay (phase 5 only; ml/loff/lm dead by then)

    int tid = threadIdx.x, lane = tid & 63, wv = tid >> 6;
    int pix0 = blockIdx.x * MT;
    int n = pix0 >> 12, hw0 = pix0 & (HWSZ - 1);
    int h = hw0 >> 6, w0 = hw0 & 63;          // 16 pixels share row h
    int c0 = lane * 4;
    int n0 = wv * 32;
    int col = lane & 15, qr = (lane >> 4) * 4;

    // ---- phase 1: dw 3x3 + bias + LN + GELU, 2 pixels per wave -> As (bf16)
    {
        float wloc[36];
        const float4* wp4 = (const float4*)(dww + c0 * 9);
#pragma unroll
        for (int k = 0; k < 9; ++k) ((float4*)wloc)[k] = wp4[k];
        float4 dwbv = *(const float4*)(dwb + c0);
        float4 lngv = *(const float4*)(lng + c0);
        float4 lnbv = *(const float4*)(lnb + c0);
        const float* yn = y + (size_t)n * HWSZ * CC;
#pragma unroll
        for (int i = 0; i < 2; ++i) {
            int pix = wv * 2 + i;
            int w = w0 + pix;
            float4 acc = dwbv;
#pragma unroll
            for (int ky = 0; ky < 3; ++ky) {
                int yy = h + ky - 1;
                if (yy < 0 || yy >= HH) continue;
#pragma unroll
                for (int kx = 0; kx < 3; ++kx) {
                    int xx = w + kx - 1;
                    if (xx < 0 || xx >= WW) continue;
                    float4 yv = *(const float4*)(yn + (size_t)((yy << 6) + xx) * CC + c0);
                    int t = ky * 3 + kx;
                    acc.x += yv.x * wloc[0 * 9 + t];
                    acc.y += yv.y * wloc[1 * 9 + t];
                    acc.z += yv.z * wloc[2 * 9 + t];
                    acc.w += yv.w * wloc[3 * 9 + t];
                }
            }
            float s1 = acc.x + acc.y + acc.z + acc.w;
            float s2 = acc.x * acc.x + acc.y * acc.y + acc.z * acc.z + acc.w * acc.w;
#pragma unroll
            for (int off = 32; off > 0; off >>= 1) {
                s1 += __shfl_xor(s1, off);
                s2 += __shfl_xor(s2, off);
            }
            float mu = s1 * (1.f / 256.f);
            float var = s2 * (1.f / 256.f) - mu * mu;
            float rs = rsqrtf(var + 1e-5f);
            float4 zv;
            zv.x = (acc.x - mu) * rs * lngv.x + lnbv.x;
            zv.y = (acc.y - mu) * rs * lngv.y + lnbv.y;
            zv.z = (acc.z - mu) * rs * lngv.z + lnbv.z;
            zv.w = (acc.w - mu) * rs * lngv.w + lnbv.w;
            zv.x = 0.5f * zv.x * (1.f + erff(zv.x * 0.70710678118654752f));
            zv.y = 0.5f * zv.y * (1.f + erff(zv.y * 0.70710678118654752f));
            zv.z = 0.5f * zv.z * (1.f + erff(zv.z * 0.70710678118654752f));
            zv.w = 0.5f * zv.w * (1.f + erff(zv.w * 0.70710678118654752f));
            *(uint2*)(As + pix * ASTR + c0) = make_uint2(pk2(zv.x, zv.y), pk2(zv.z, zv.w));
        }
    }
    short8 bf[8][2];
    prefetch_b(Whb, lane, n0, bf);            // drains under the barrier
    __syncthreads();

    // ---- phase 2: heads GEMM -> loff / ml (LDS only)
    {
        f32x4 acc[2];
        acc[0] = (f32x4){0.f, 0.f, 0.f, 0.f};
        acc[1] = (f32x4){0.f, 0.f, 0.f, 0.f};
        mfma_acc(As, bf, lane, acc);
#pragma unroll
        for (int nt = 0; nt < 2; ++nt) {
            int o = n0 + nt * 16 + col;
            float bo = bh[o];
#pragma unroll
            for (int r = 0; r < 4; ++r) {
                float v = acc[nt][r] + bo;
                int pix = qr + r;
                if (o < 144) loff[pix * 144 + o] = v;
                else if (o < 216) ml[pix * 76 + (o - 144)] = v;
            }
        }
    }
    __syncthreads();

    // ---- phase 3: per-group softmax -> lm
    if (tid < 128) {
        int pi = tid >> 3, g = tid & 7;
        const float* row = ml + pi * 76 + g * 9;
        float mx = -1e30f;
#pragma unroll
        for (int p = 0; p < 9; ++p) mx = fmaxf(mx, row[p]);
        float e[9], s = 0.f;
#pragma unroll
        for (int p = 0; p < 9; ++p) { e[p] = __expf(row[p] - mx); s += e[p]; }
        float inv = 1.f / s;
        float* mp = lm + pi * 72 + g * 9;
#pragma unroll
        for (int p = 0; p < 9; ++p) mp[p] = e[p] * inv;
    }
    __syncthreads();

    // ---- phase 4: DCN bilinear gather, 2 pixels per wave -> As (bf16)
    {
        int g = lane >> 3;
        const float* xpn = xp + (size_t)n * HWSZ * CC;
#pragma unroll
        for (int i = 0; i < 2; ++i) {
            int pix = wv * 2 + i;
            int w = w0 + pix;
            float4 acc = make_float4(0.f, 0.f, 0.f, 0.f);
#pragma unroll
            for (int p = 0; p < 9; ++p) {
                float ox = loff[pix * 144 + (g * 9 + p) * 2];
                float oy = loff[pix * 144 + (g * 9 + p) * 2 + 1];
                float px = (float)(w + p / 3) + ox;
                float py = (float)(h + p % 3) + oy;
                float fx = floorf(px), fy = floorf(py);
                float wx1 = px - fx, wy1 = py - fy;
                int x0 = (int)fx, y0 = (int)fy;
                int x1 = x0 + 1, y1 = y0 + 1;
                float mval = lm[pix * 72 + g * 9 + p];
                float w00 = (1.f - wx1) * (1.f - wy1) * mval;
                float w10 = wx1 * (1.f - wy1) * mval;
                float w01 = (1.f - wx1) * wy1 * mval;
                float w11 = wx1 * wy1 * mval;
                if (x0 >= 1 && x0 <= WW && y0 >= 1 && y0 <= HH) {
                    float4 s = *(const float4*)(xpn + (size_t)(((y0 - 1) << 6) + (x0 - 1)) * CC + c0);
                    acc.x += w00 * s.x; acc.y += w00 * s.y; acc.z += w00 * s.z; acc.w += w00 * s.w;
                }
                if (x1 >= 1 && x1 <= WW && y0 >= 1 && y0 <= HH) {
                    float4 s = *(const float4*)(xpn + (size_t)(((y0 - 1) << 6) + (x1 - 1)) * CC + c0);
                    acc.x += w10 * s.x; acc.y += w10 * s.y; acc.z += w10 * s.z; acc.w += w10 * s.w;
                }
                if (x0 >= 1 && x0 <= WW && y1 >= 1 && y1 <= HH) {
                    float4 s = *(const float4*)(xpn + (size_t)(((y1 - 1) << 6) + (x0 - 1)) * CC + c0);
                    acc.x += w01 * s.x; acc.y += w01 * s.y; acc.z += w01 * s.z; acc.w += w01 * s.w;
                }
                if (x1 >= 1 && x1 <= WW && y1 >= 1 && y1 <= HH) {
                    float4 s = *(const float4*)(xpn + (size_t)(((y1 - 1) << 6) + (x1 - 1)) * CC + c0);
                    acc.x += w11 * s.x; acc.y += w11 * s.y; acc.z += w11 * s.z; acc.w += w11 * s.w;
                }
            }
            *(uint2*)(As + pix * ASTR + c0) = make_uint2(pk2(acc.x, acc.y), pk2(acc.z, acc.w));
        }
    }
    prefetch_b(Wopb, lane, n0, bf);           // drains under the barrier
    __syncthreads();

    // ---- phase 5: outproj GEMM + BN2 + SiLU -> xs
    {
        f32x4 acc[2];
        acc[0] = (f32x4){0.f, 0.f, 0.f, 0.f};
        acc[1] = (f32x4){0.f, 0.f, 0.f, 0.f};
        mfma_acc(As, bf, lane, acc);
#pragma unroll
        for (int nt = 0; nt < 2; ++nt) {
            int o = n0 + nt * 16 + col;
            float bo = opb[o], sc = sc2[o], sh = sh2[o];
#pragma unroll
            for (int r = 0; r < 4; ++r)
                xs[(qr + r) * 260 + o] = silu_f((acc[nt][r] + bo) * sc + sh);
        }
    }
    __syncthreads();

    // ---- store NCHW: 4 lanes cover one channel's 16 floats (64-B segments)
    {
        int i4 = (tid & 3) * 4;
        int obase = tid >> 2;                 // 0..127
        float* on = out + (size_t)n * CC * HWSZ + hw0 + i4;
#pragma unroll
        for (int pass = 0; pass < 2; ++pass) {
            int o = obase + pass * 128;
            float4 ov;
            ov.x = xs[(i4 + 0) * 260 + o];
            ov.y = xs[(i4 + 1) * 260 + o];
            ov.z = xs[(i4 + 2) * 260 + o];
            ov.w = xs[(i4 + 3) * 260 + o];
            *(float4*)(on + (size_t)o * HWSZ) = ov;
        }
    }
}

// ---------------------------------------------------------------------------
extern "C" void kernel_launch(void* const* d_in, const int* in_sizes, int n_in,
                              void* d_out, int out_size, void* d_ws, size_t ws_size,
                              hipStream_t stream) {
    const float* x        = (const float*)d_in[0];
    const float* conv1_w  = (const float*)d_in[1];
    const float* bn1_g    = (const float*)d_in[2];
    const float* bn1_b    = (const float*)d_in[3];
    const float* bn1_m    = (const float*)d_in[4];
    const float* bn1_v    = (const float*)d_in[5];
    const float* inproj_w = (const float*)d_in[6];
    const float* inproj_b = (const float*)d_in[7];
    const float* dw_w     = (const float*)d_in[8];
    const float* dw_b     = (const float*)d_in[9];
    const float* ln_g     = (const float*)d_in[10];
    const float* ln_b     = (const float*)d_in[11];
    const float* off_w    = (const float*)d_in[12];
    const float* off_b    = (const float*)d_in[13];
    const float* mask_w   = (const float*)d_in[14];
    const float* mask_b   = (const float*)d_in[15];
    const float* outproj_w = (const float*)d_in[16];
    const float* outproj_b = (const float*)d_in[17];
    const float* bn2_g    = (const float*)d_in[18];
    const float* bn2_b    = (const float*)d_in[19];
    const float* bn2_m    = (const float*)d_in[20];
    const float* bn2_v    = (const float*)d_in[21];
    float* out = (float*)d_out;

    short* Wc1b = (short*)d_ws;            // 65536 shorts each
    short* Wipb = Wc1b + 65536;
    short* Whb  = Wipb + 65536;
    short* Wopb = Whb + 65536;
    float* fp   = (float*)(Wopb + 65536);
    float* bh   = fp;
    float* sc1  = bh + 256;
    float* sh1  = sc1 + 256;
    float* sc2  = sh1 + 256;
    float* sh2  = sc2 + 256;
    float* y    = sh2 + 256;               // 2097152 (NHWC fp32)
    float* xp   = y + 2097152;             // 2097152 (NHWC fp32)

    k_prep<<<dim3(CC), dim3(CC), 0, stream>>>(conv1_w, inproj_w, off_w, mask_w, outproj_w,
                                              off_b, mask_b, bn1_g, bn1_b, bn1_m, bn1_v,
                                              bn2_g, bn2_b, bn2_m, bn2_v,
                                              Wc1b, Wipb, Whb, Wopb, bh, sc1, sh1, sc2, sh2);
    k_conv_in<<<dim3(NPIX / MT), dim3(512), 0, stream>>>(x, Wc1b, Wipb, sc1, sh1, inproj_b, y, xp);
    k_tail<<<dim3(NPIX / MT), dim3(512), 0, stream>>>(y, xp, dw_w, dw_b, ln_g, ln_b,
                                                      Whb, bh, Wopb, outproj_b, sc2, sh2, out);
}